// Round 9
// baseline (50.653 us; speedup 1.0000x reference)
//
#include <hip/hip_runtime.h>

// Problem constants (from reference)
#define N_IDEAS 5
#define N_EXPERTS 10
#define OUT_DIM 784          // 28*28
#define CHUNKS 196           // OUT_DIM / 4 (float4 chunks per sample)
#define BATCH 32768

// Round-2 kernel verbatim (best known: 27.2 us single-launch).
// THIS ROUND IS A DIAGNOSTIC: kernel_launch launches it TWICE back-to-back
// (second launch writes identical values -> deterministic, output valid).
// dur2 = F + 2S, with known F + S = 27.2 -> separates fixed replay/launch
// overhead F from steady-state memory time S.
#define CTILE 28             // chunks per tile (196 = 7*28)
#define NTILES 7
#define SPB 128              // samples per block (32768 = 256*128)
#define BLOCK 256
#define ITERS ((SPB * CTILE) / BLOCK)   // = 14, exact

__global__ __launch_bounds__(BLOCK) void moe_gather_gemv_lds(
    const float* __restrict__ x,      // [B, 5]
    const int* __restrict__ labels,   // [B]
    const float* __restrict__ W,      // [E, 784, 5]
    const float* __restrict__ b,      // [E, 784]
    float4* __restrict__ out)         // [B*196] float4 view of [B,784]
{
    __shared__ float Wl[N_EXPERTS * CTILE * 20];   // [e][c][20]
    __shared__ float bl[N_EXPERTS * CTILE * 4];    // [e][c][4]
    __shared__ float xl[SPB * N_IDEAS];            // [s][5]
    __shared__ int   ll[SPB];                      // [s]

    const int tid = threadIdx.x;
    const int sg  = blockIdx.x;       // sample group: samples [sg*128, +128)
    const int ct  = blockIdx.y;       // chunk tile:   chunks  [ct*28,  +28)

    {
        const float4* Wg = (const float4*)W;
        float4* Wl4 = (float4*)Wl;
        for (int i = tid; i < N_EXPERTS * 140; i += BLOCK) {
            const int e = i / 140;
            const int r = i - e * 140;
            Wl4[e * 140 + r] = Wg[e * 980 + ct * 140 + r];
        }
        const float4* bg = (const float4*)b;
        float4* bl4 = (float4*)bl;
        for (int i = tid; i < N_EXPERTS * CTILE; i += BLOCK) {
            const int e = i / CTILE;
            const int r = i - e * CTILE;
            bl4[e * CTILE + r] = bg[e * 196 + ct * CTILE + r];
        }
        const float4* xg = (const float4*)x;
        float4* xl4 = (float4*)xl;
        for (int i = tid; i < (SPB * N_IDEAS) / 4; i += BLOCK)
            xl4[i] = xg[sg * 160 + i];
        const int4* lg = (const int4*)labels;
        int4* ll4 = (int4*)ll;
        if (tid < SPB / 4)
            ll4[tid] = lg[sg * (SPB / 4) + tid];
    }
    __syncthreads();

    const size_t outBase = (size_t)sg * SPB * CHUNKS + (size_t)ct * CTILE;
#pragma unroll
    for (int k = 0; k < ITERS; ++k) {
        const int i   = tid + k * BLOCK;        // 0 .. 3583
        const int s_l = i / CTILE;              // local sample 0..127
        const int c_l = i - s_l * CTILE;        // local chunk  0..27
        const int e   = ll[s_l];

        const float* xp = &xl[s_l * N_IDEAS];
        const float x0 = xp[0], x1 = xp[1], x2 = xp[2], x3 = xp[3], x4 = xp[4];

        const float4* wp = (const float4*)&Wl[(e * CTILE + c_l) * 20];
        const float4 w0 = wp[0], w1 = wp[1], w2 = wp[2], w3 = wp[3], w4 = wp[4];
        const float4* bp = (const float4*)&bl[(e * CTILE + c_l) * 4];
        const float4 bb = bp[0];

        float4 r;
        r.x = bb.x + w0.x*x0 + w0.y*x1 + w0.z*x2 + w0.w*x3 + w1.x*x4;
        r.y = bb.y + w1.y*x0 + w1.z*x1 + w1.w*x2 + w2.x*x3 + w2.y*x4;
        r.z = bb.z + w2.z*x0 + w2.w*x1 + w3.x*x2 + w3.y*x3 + w3.z*x4;
        r.w = bb.w + w3.w*x0 + w4.x*x1 + w4.y*x2 + w4.z*x3 + w4.w*x4;

        out[outBase + (size_t)s_l * CHUNKS + c_l] = r;
    }
}

extern "C" void kernel_launch(void* const* d_in, const int* in_sizes, int n_in,
                              void* d_out, int out_size, void* d_ws, size_t ws_size,
                              hipStream_t stream) {
    const float* x      = (const float*)d_in[0];
    const int*   labels = (const int*)d_in[1];
    const float* W      = (const float*)d_in[2];
    const float* b      = (const float*)d_in[3];
    float4* out = (float4*)d_out;

    dim3 grid(BATCH / SPB, NTILES);   // 256 x 7 = 1792 blocks
    // DIAGNOSTIC: two identical launches. dur2 = F + 2S (F = fixed overhead,
    // S = steady-state kernel time; F + S = 27.2 us from round 2).
    moe_gather_gemv_lds<<<grid, dim3(BLOCK), 0, stream>>>(x, labels, W, b, out);
    moe_gather_gemv_lds<<<grid, dim3(BLOCK), 0, stream>>>(x, labels, W, b, out);
}

// Round 10
// 34.032 us; speedup vs baseline: 1.4884x; 1.4884x over previous
//
#include <hip/hip_runtime.h>
#include <hip/hip_fp16.h>

// Problem constants (from reference)
#define N_IDEAS 5
#define N_EXPERTS 10
#define OUT_DIM 784          // 28*28
#define CHUNKS 196           // OUT_DIM / 4
#define BATCH 32768
#define CTILE 98             // chunks per tile (196 = 2*98) -> 1568B row segments
#define NTILES 2
#define SPB 32               // samples per block
#define BLOCK 256
#define OPB (SPB * CTILE)    // 3136 float4 outputs per block
#define NITER ((OPB + BLOCK - 1) / BLOCK)   // 13 (last iter 1/4 active)

// Fragmentation experiment: same operand math as R2, but store segments grow
// 448B -> 1568B (half-rows). W tile for 98 chunks only fits LDS as fp16:
// 10 experts x 98 chunks x 20 weights x 2B = 39.2 KB (err ~2e-3 << 8.4e-2).
// x/labels/bias come straight from L1 (broadcast / 15.7KB resident).
// 4 blocks/CU (LDS 4x39.2 = 157KB), grid 1024x2 = exactly 8 blocks/CU.
__global__ __launch_bounds__(BLOCK, 4) void moe_seq98(
    const float* __restrict__ x,      // [B, 5]
    const int* __restrict__ labels,   // [B]
    const float* __restrict__ W,      // [E, 784, 5]
    const float* __restrict__ b,      // [E, 784]
    float4* __restrict__ out)         // [B*196]
{
    __shared__ unsigned int Wl[N_EXPERTS * CTILE * 10];   // fp16 pairs, 39.2 KB

    const int tid = threadIdx.x;
    // XCD-contiguous swizzle: 1024 x-blocks, 8 XCDs -> each XCD gets a
    // contiguous 128-block (50 MB) output span. 1024 % 8 == 0 -> bijective.
    const int bx = blockIdx.x;
    const int sg = (bx & 7) * (1024 / 8) + (bx >> 3);
    const int ct = blockIdx.y;

    // ---- stage W tile as packed fp16 (one barrier total) ----
    const float4* Wg = (const float4*)W;                  // 980 f4 per expert
    for (int p = tid; p < N_EXPERTS * CTILE * 5; p += BLOCK) {   // 4900 f4
        const int e   = p / (CTILE * 5);
        const int rem = p - e * (CTILE * 5);
        const int c   = rem / 5, r = rem - c * 5;
        const float4 v = Wg[e * 980 + (ct * CTILE + c) * 5 + r];
        const unsigned int u0 =
            ((unsigned int)__half_as_ushort(__float2half(v.x))) |
            ((unsigned int)__half_as_ushort(__float2half(v.y)) << 16);
        const unsigned int u1 =
            ((unsigned int)__half_as_ushort(__float2half(v.z))) |
            ((unsigned int)__half_as_ushort(__float2half(v.w)) << 16);
        *(uint2*)&Wl[(e * CTILE + c) * 10 + r * 2] = make_uint2(u0, u1);
    }
    __syncthreads();

#define LOH(u) __half2float(__ushort_as_half((unsigned short)((u) & 0xffffu)))
#define HIH(u) __half2float(__ushort_as_half((unsigned short)((u) >> 16)))

    const float4* bg4 = (const float4*)b;                 // 196 f4 per expert

    for (int it = 0; it < NITER; ++it) {
        const int i   = it * BLOCK + tid;                 // 0..3327
        const bool act = (i < OPB);
        const int ii  = act ? i : 0;
        const int s_l = ii / CTILE;                       // 0..31
        const int c_l = ii - s_l * CTILE;                 // 0..97
        const int sid = sg * SPB + s_l;

        const int e = labels[sid];                        // L1 broadcast
        const float* xp = x + (size_t)sid * N_IDEAS;      // L1 broadcast
        const float x0 = xp[0], x1 = xp[1], x2 = xp[2], x3 = xp[3], x4 = xp[4];

        const uint2* wp = (const uint2*)&Wl[(e * CTILE + c_l) * 10];
        const uint2 q0 = wp[0], q1 = wp[1], q2 = wp[2], q3 = wp[3], q4 = wp[4];
        const float4 bb = bg4[(size_t)e * 196 + ct * CTILE + c_l];   // L1 tile

        const float f0  = LOH(q0.x), f1  = HIH(q0.x), f2  = LOH(q0.y), f3  = HIH(q0.y);
        const float f4  = LOH(q1.x), f5  = HIH(q1.x), f6  = LOH(q1.y), f7  = HIH(q1.y);
        const float f8  = LOH(q2.x), f9  = HIH(q2.x), f10 = LOH(q2.y), f11 = HIH(q2.y);
        const float f12 = LOH(q3.x), f13 = HIH(q3.x), f14 = LOH(q3.y), f15 = HIH(q3.y);
        const float f16 = LOH(q4.x), f17 = HIH(q4.x), f18 = LOH(q4.y), f19 = HIH(q4.y);

        float4 r;
        r.x = bb.x + f0 *x0 + f1 *x1 + f2 *x2 + f3 *x3 + f4 *x4;
        r.y = bb.y + f5 *x0 + f6 *x1 + f7 *x2 + f8 *x3 + f9 *x4;
        r.z = bb.z + f10*x0 + f11*x1 + f12*x2 + f13*x3 + f14*x4;
        r.w = bb.w + f15*x0 + f16*x1 + f17*x2 + f18*x3 + f19*x4;

        if (act)
            out[(size_t)sid * CHUNKS + ct * CTILE + c_l] = r;  // 1568B segments
    }
#undef LOH
#undef HIH
}

extern "C" void kernel_launch(void* const* d_in, const int* in_sizes, int n_in,
                              void* d_out, int out_size, void* d_ws, size_t ws_size,
                              hipStream_t stream) {
    const float* x      = (const float*)d_in[0];
    const int*   labels = (const int*)d_in[1];
    const float* W      = (const float*)d_in[2];
    const float* b      = (const float*)d_in[3];
    float4* out = (float4*)d_out;

    dim3 grid(BATCH / SPB, NTILES);    // 1024 x 2 = 2048 blocks = 8/CU exact
    moe_seq98<<<grid, dim3(BLOCK), 0, stream>>>(x, labels, W, b, out);
}